// Round 4
// baseline (717.041 us; speedup 1.0000x reference)
//
#include <hip/hip_runtime.h>
#include <hip/hip_bf16.h>

// SwarmAttentionHead: out = softmax(mask(QK^T/sqrt(D))) @ V @ Wo^T + bo
// N=8192, D=256. bf16 MFMA for all matmuls, f32 softmax/accum.
// Adjacency pre-packed to a bitmask (8MB) by repack_kernel.
//
// ws layout:
//   [0,   4M)  Qb  bf16 [8192][256]   (pre-scaled by 1/16)
//   [4M,  8M)  Kb  bf16 [8192][256]
//   [8M, 12M)  VT  bf16 [256][8192]   (V transposed)
//   [12M,16M)  CX  bf16 [8192][256]   (context)
//   [16M,24M)  bm  u64 [8192][128]    (adjacency bitmask)
//   [24M, ..)  pacc [8][8192][256] f32 (88.5M total) or bf16 (56.5M total)
//   pm/pl f32 [8][8192] directly after pacc

#define LOG2E 1.44269504088896340736f
#define MASKVAL -3.0e38f   // masked score sentinel
#define MINIT   -1.0e38f   // running-max init; MUST differ from MASKVAL (x-x=0 bug)

using f32x4 = __attribute__((ext_vector_type(4))) float;
using s16x8 = __attribute__((ext_vector_type(8))) short;
using s16x4 = __attribute__((ext_vector_type(4))) short;

__device__ __forceinline__ void gl_lds16(void* l, const void* g) {
  // async 16B global->LDS; LDS dest is wave-linear (lane*16), source carries swizzle
  __builtin_amdgcn_global_load_lds(
      (const __attribute__((address_space(1))) void*)g,
      (__attribute__((address_space(3))) void*)l, 16, 0, 0);
}

__device__ __forceinline__ short f2bf(float x) {
  union { float f; unsigned u; } v; v.f = x;
  unsigned r = v.u + 0x7fffu + ((v.u >> 16) & 1u);   // RNE, finite inputs only
  return (short)(r >> 16);
}

__device__ __forceinline__ s16x8 cvt_frag(f32x4 a, f32x4 b) {
  s16x8 r;
  r[0]=f2bf(a[0]); r[1]=f2bf(a[1]); r[2]=f2bf(a[2]); r[3]=f2bf(a[3]);
  r[4]=f2bf(b[0]); r[5]=f2bf(b[1]); r[6]=f2bf(b[2]); r[7]=f2bf(b[3]);
  return r;
}

__device__ __forceinline__ f32x4 mfma16(s16x8 a, s16x8 b, f32x4 c) {
  return __builtin_amdgcn_mfma_f32_16x16x32_bf16(a, b, c, 0, 0, 0);
}

// ---------------------------------------------------------------------------
// Adjacency -> bitmask. Row per block; wave covers 64 cols per ballot.
// 256B coalesced read per wave-instr; 8MB output.
// ---------------------------------------------------------------------------
__global__ __launch_bounds__(256)
void repack_kernel(const int* __restrict__ adj, unsigned long long* __restrict__ bm)
{
  const int row = blockIdx.x;
  const int w = threadIdx.x >> 6, lane = threadIdx.x & 63;
  const int* src = adj + (size_t)row * 8192 + w * 2048;
  unsigned long long* dst = bm + (size_t)row * 128 + w * 32;
#pragma unroll 4
  for (int it = 0; it < 32; ++it) {
    int x = src[it * 64 + lane];
    unsigned long long b = __ballot(x != 0);
    if (lane == 0) dst[it] = b;
  }
}

// ---------------------------------------------------------------------------
// Fused Q/K/V projection: {Q,K,V}[i][j] = E[i]·W{q,k,v}[j] + b (Q scaled 1/16,
// V written transposed). 64x64 tile, 4 waves 2x2, BK=64, E staged ONCE.
// ---------------------------------------------------------------------------
__global__ __launch_bounds__(256, 2)
void qkv_kernel(const float* __restrict__ E,
                const float* __restrict__ Wq, const float* __restrict__ bq,
                const float* __restrict__ Wk, const float* __restrict__ bk,
                const float* __restrict__ Wv, const float* __restrict__ bv,
                unsigned short* __restrict__ Qb, unsigned short* __restrict__ Kb,
                unsigned short* __restrict__ VT)
{
  __shared__ __align__(16) char ldsA[16384];
  __shared__ __align__(16) char ldsB[3][16384];
  const int tid = threadIdx.x;
  const int lane = tid & 63, w = tid >> 6;
  const int wr = w >> 1, wc = w & 1;
  const int l15 = lane & 15, lhi = lane >> 4;
  const int m0 = blockIdx.x * 64, n0 = blockIdx.y * 64;
  const float* Ws[3] = {Wq, Wk, Wv};

  f32x4 acc[3][2][2] = {};

  for (int k0 = 0; k0 < 256; k0 += 64) {
#pragma unroll
    for (int i = 0; i < 4; ++i) {
      int o = tid * 16 + i * 4096;
      int row = o >> 8, inrow = o & 255;
      gl_lds16(ldsA + o, (const char*)E + (size_t)(m0 + row) * 1024 + k0 * 4 + (inrow ^ ((row & 7) << 4)));
    }
#pragma unroll
    for (int mtx = 0; mtx < 3; ++mtx)
#pragma unroll
      for (int i = 0; i < 4; ++i) {
        int o = tid * 16 + i * 4096;
        int row = o >> 8, inrow = o & 255;
        gl_lds16(ldsB[mtx] + o, (const char*)Ws[mtx] + (size_t)(n0 + row) * 1024 + k0 * 4 + (inrow ^ ((row & 7) << 4)));
      }
    __syncthreads();

#pragma unroll
    for (int ks = 0; ks < 2; ++ks) {
      s16x8 af[2];
#pragma unroll
      for (int m = 0; m < 2; ++m) {
        int row = wr * 32 + m * 16 + l15;
        int c = ks * 128 + lhi * 32;
        f32x4 lo = *(const f32x4*)(ldsA + row * 256 + (c ^ ((row & 7) << 4)));
        f32x4 hi = *(const f32x4*)(ldsA + row * 256 + ((c + 16) ^ ((row & 7) << 4)));
        af[m] = cvt_frag(lo, hi);
      }
#pragma unroll
      for (int mtx = 0; mtx < 3; ++mtx) {
        s16x8 bfr[2];
#pragma unroll
        for (int n = 0; n < 2; ++n) {
          int row = wc * 32 + n * 16 + l15;
          int c = ks * 128 + lhi * 32;
          f32x4 lo = *(const f32x4*)(ldsB[mtx] + row * 256 + (c ^ ((row & 7) << 4)));
          f32x4 hi = *(const f32x4*)(ldsB[mtx] + row * 256 + ((c + 16) ^ ((row & 7) << 4)));
          bfr[n] = cvt_frag(lo, hi);
        }
#pragma unroll
        for (int m = 0; m < 2; ++m)
#pragma unroll
          for (int n = 0; n < 2; ++n)
            acc[mtx][m][n] = mfma16(af[m], bfr[n], acc[mtx][m][n]);
      }
    }
    __syncthreads();
  }

  // epilogue: row = m0+wr*32+m*16+lhi*4+r, col = n0+wc*32+n*16+l15
#pragma unroll
  for (int n = 0; n < 2; ++n) {
    int col = n0 + wc * 32 + n * 16 + l15;
    float bvq = bq[col], bvk = bk[col], bvv = bv[col];
#pragma unroll
    for (int m = 0; m < 2; ++m) {
      int rbase = m0 + wr * 32 + m * 16 + lhi * 4;
#pragma unroll
      for (int r = 0; r < 4; ++r) {
        Qb[(size_t)(rbase + r) * 256 + col] = (unsigned short)f2bf((acc[0][m][n][r] + bvq) * 0.0625f);
        Kb[(size_t)(rbase + r) * 256 + col] = (unsigned short)f2bf(acc[1][m][n][r] + bvk);
      }
      s16x4 pk;
#pragma unroll
      for (int r = 0; r < 4; ++r) pk[r] = f2bf(acc[2][m][n][r] + bvv);
      *(s16x4*)(VT + (size_t)col * 8192 + rbase) = pk;
    }
  }
}

// ---------------------------------------------------------------------------
// Output projection: out[i][j] = CX[i]·Wo[j] + bo[j]  (bf16 A, f32 out)
// ---------------------------------------------------------------------------
__global__ __launch_bounds__(256, 4)
void projo_kernel(const unsigned short* __restrict__ Ap, const float* __restrict__ W,
                  const float* __restrict__ bias, float* __restrict__ outp)
{
  __shared__ __align__(16) char ldsA[8192];
  __shared__ __align__(16) char ldsB[16384];
  const int tid = threadIdx.x;
  const int lane = tid & 63, w = tid >> 6;
  const int wr = w >> 1, wc = w & 1;
  const int l15 = lane & 15, lhi = lane >> 4;
  const int m0 = blockIdx.x * 64, n0 = blockIdx.y * 64;

  f32x4 acc[2][2] = {};

  for (int k0 = 0; k0 < 256; k0 += 64) {
#pragma unroll
    for (int i = 0; i < 2; ++i) {
      int o = tid * 16 + i * 4096;
      int row = o >> 7, inrow = o & 127;
      gl_lds16(ldsA + o, (const char*)Ap + (size_t)(m0 + row) * 512 + k0 * 2 + (inrow ^ ((row & 7) << 4)));
    }
#pragma unroll
    for (int i = 0; i < 4; ++i) {
      int o = tid * 16 + i * 4096;
      int row = o >> 8, inrow = o & 255;
      gl_lds16(ldsB + o, (const char*)W + (size_t)(n0 + row) * 1024 + k0 * 4 + (inrow ^ ((row & 7) << 4)));
    }
    __syncthreads();

#pragma unroll
    for (int ks = 0; ks < 2; ++ks) {
      s16x8 af[2], bfr[2];
#pragma unroll
      for (int m = 0; m < 2; ++m) {
        int row = wr * 32 + m * 16 + l15;
        int c = ks * 64 + lhi * 16;
        af[m] = *(const s16x8*)(ldsA + row * 128 + (c ^ ((row & 7) << 4)));
      }
#pragma unroll
      for (int n = 0; n < 2; ++n) {
        int row = wc * 32 + n * 16 + l15;
        int c = ks * 128 + lhi * 32;
        f32x4 lo = *(const f32x4*)(ldsB + row * 256 + (c ^ ((row & 7) << 4)));
        f32x4 hi = *(const f32x4*)(ldsB + row * 256 + ((c + 16) ^ ((row & 7) << 4)));
        bfr[n] = cvt_frag(lo, hi);
      }
#pragma unroll
      for (int m = 0; m < 2; ++m)
#pragma unroll
        for (int n = 0; n < 2; ++n)
          acc[m][n] = mfma16(af[m], bfr[n], acc[m][n]);
    }
    __syncthreads();
  }

#pragma unroll
  for (int n = 0; n < 2; ++n) {
    int col = n0 + wc * 32 + n * 16 + l15;
    float bv = bias[col];
#pragma unroll
    for (int m = 0; m < 2; ++m) {
      int rbase = m0 + wr * 32 + m * 16 + lhi * 4;
#pragma unroll
      for (int r = 0; r < 4; ++r)
        outp[(size_t)(rbase + r) * 256 + col] = acc[m][n][r] + bv;
    }
  }
}

// ---------------------------------------------------------------------------
// Flash attention, bitmask-masked. 4 waves x 32 q-rows (BM=128), KVBLK=64.
// 80KB LDS -> 2 blocks/CU; cross-block TLP hides stage drain.
// blockIdx.x = qt*SPLIT + sp (sp in low bits: same-sp blocks share one XCD's L2).
// ---------------------------------------------------------------------------
template<int SPLIT, bool DIRECT, bool PACC_BF16>
__global__ __launch_bounds__(256, 2)
void attn_kernel(const unsigned short* __restrict__ Qb, const char* __restrict__ Kb,
                 const char* __restrict__ VbT, const unsigned long long* __restrict__ bm,
                 void* __restrict__ pacc, float* __restrict__ pm,
                 float* __restrict__ pl, unsigned short* __restrict__ CX)
{
  __shared__ __align__(16) char ldsK[32768];   // [64 kv][512B], swizzled
  __shared__ __align__(16) char ldsV[32768];   // [256 d][128B], swizzled
  __shared__ __align__(16) char ldsP[16384];   // 4 waves x [32 q][128B], swizzled
  const int tid = threadIdx.x, lane = tid & 63, w = tid >> 6;
  const int l15 = lane & 15, lhi = lane >> 4;
  const int qt = blockIdx.x / SPLIT, sp = blockIdx.x % SPLIT;
  const int q0 = qt * 128 + w * 32;
  char* myP = ldsP + w * 4096;
  const int kv_begin = sp * (8192 / SPLIT);
  const int NT = 8192 / SPLIT / 64;

  // Q fragments: 2 frags x 8 k-slices (64 VGPR), pre-scaled by 1/16 in Qb
  s16x8 qf[2][8];
#pragma unroll
  for (int f = 0; f < 2; ++f) {
    const unsigned short* qp = Qb + (size_t)(q0 + f * 16 + l15) * 256 + lhi * 8;
#pragma unroll
    for (int ks = 0; ks < 8; ++ks) qf[f][ks] = *(const s16x8*)(qp + ks * 32);
  }

  f32x4 ctx[2][16] = {};
  float m_run[2][4], l_run[2][4];
#pragma unroll
  for (int f = 0; f < 2; ++f)
#pragma unroll
    for (int r = 0; r < 4; ++r) { m_run[f][r] = MINIT; l_run[f][r] = 0.f; }

  for (int t = 0; t < NT; ++t) {
    const int kv0 = kv_begin + t * 64;

    // stage K and V^T tiles (single-buffered), source-swizzled
    {
      const char* kg = Kb + (size_t)kv0 * 512;
#pragma unroll
      for (int i = 0; i < 8; ++i) {
        int o = tid * 16 + i * 4096;
        int row = o >> 9, inrow = o & 511;
        gl_lds16(ldsK + o, kg + row * 512 + (inrow ^ ((row & 7) << 4)));
      }
#pragma unroll
      for (int i = 0; i < 8; ++i) {
        int o = tid * 16 + i * 4096;
        int row = o >> 7, inrow = o & 127;
        gl_lds16(ldsV + o, VbT + (size_t)row * 16384 + (size_t)kv0 * 2 + (inrow ^ ((row & 7) << 4)));
      }
    }

    // bitmask loads (broadcast across 16 lanes, L2-resident slice);
    // issued before the barrier, consumed after QK^T
    unsigned long long bmv[2][4];
#pragma unroll
    for (int f = 0; f < 2; ++f) {
      const unsigned long long* bp = bm + (size_t)(q0 + f * 16 + lhi * 4) * 128 + (kv0 >> 6);
#pragma unroll
      for (int r = 0; r < 4; ++r) bmv[f][r] = bp[(size_t)r * 128];
    }

    __syncthreads();   // vmcnt(0) drain: K/V staged

    // S = Q @ K^T : each kf read feeds both q-frags
    f32x4 sacc[2][4] = {};
    __builtin_amdgcn_s_setprio(1);
#pragma unroll
    for (int ks = 0; ks < 8; ++ks)
#pragma unroll
      for (int cg = 0; cg < 4; ++cg) {
        int row = cg * 16 + l15;
        s16x8 kf = *(const s16x8*)(ldsK + row * 512 + ((ks * 64 + lhi * 16) ^ ((row & 7) << 4)));
        sacc[0][cg] = mfma16(qf[0][ks], kf, sacc[0][cg]);
        sacc[1][cg] = mfma16(qf[1][ks], kf, sacc[1][cg]);
      }
    __builtin_amdgcn_s_setprio(0);

    // fold mask pre-max: bit (cg*16+l15) of bmv[f][r]
#pragma unroll
    for (int f = 0; f < 2; ++f)
#pragma unroll
      for (int r = 0; r < 4; ++r) {
        unsigned long long ms = bmv[f][r] >> l15;
#pragma unroll
        for (int cg = 0; cg < 4; ++cg)
          if (!((unsigned)(ms >> (cg * 16)) & 1u)) sacc[f][cg][r] = MASKVAL;
      }

    // row max: over cg, then across the 16 lanes (bits 0-3)
    float tmax[2][4];
#pragma unroll
    for (int f = 0; f < 2; ++f)
#pragma unroll
      for (int r = 0; r < 4; ++r)
        tmax[f][r] = fmaxf(fmaxf(sacc[f][0][r], sacc[f][1][r]),
                           fmaxf(sacc[f][2][r], sacc[f][3][r]));
#pragma unroll
    for (int mk = 1; mk <= 8; mk <<= 1)
#pragma unroll
      for (int f = 0; f < 2; ++f)
#pragma unroll
        for (int r = 0; r < 4; ++r)
          tmax[f][r] = fmaxf(tmax[f][r], __shfl_xor(tmax[f][r], mk, 64));

    // T13 defer-max: rescale only if some row's max grew by > 8
    float need = MASKVAL;
#pragma unroll
    for (int f = 0; f < 2; ++f)
#pragma unroll
      for (int r = 0; r < 4; ++r)
        need = fmaxf(need, tmax[f][r] - m_run[f][r]);
    if (!__all(need <= 8.0f)) {
#pragma unroll
      for (int f = 0; f < 2; ++f) {
        f32x4 fv;
#pragma unroll
        for (int r = 0; r < 4; ++r) {
          float mnew = fmaxf(m_run[f][r], tmax[f][r]);
          float fs = __builtin_amdgcn_exp2f((m_run[f][r] - mnew) * LOG2E);
          m_run[f][r] = mnew; l_run[f][r] *= fs; fv[r] = fs;
        }
#pragma unroll
        for (int dm = 0; dm < 16; ++dm) ctx[f][dm] *= fv;
      }
    }

    // p = e^{s-m} (masked -> ~0 via sentinel), accumulate l, stage P bf16
#pragma unroll
    for (int f = 0; f < 2; ++f)
#pragma unroll
      for (int cg = 0; cg < 4; ++cg)
#pragma unroll
        for (int r = 0; r < 4; ++r) {
          float p = __builtin_amdgcn_exp2f((sacc[f][cg][r] - m_run[f][r]) * LOG2E);
          l_run[f][r] += p;
          int row = f * 16 + lhi * 4 + r;
          int cb = (cg * 16 + l15) * 2;
          *(short*)(myP + row * 128 + (cb ^ ((row & 7) << 4))) = f2bf(p);
        }

    // ctx += P @ V : each vf read feeds both q-frags
    __builtin_amdgcn_s_setprio(1);
#pragma unroll
    for (int ks = 0; ks < 2; ++ks) {
      s16x8 pf[2];
#pragma unroll
      for (int f = 0; f < 2; ++f) {
        int prow = f * 16 + l15;
        pf[f] = *(const s16x8*)(myP + prow * 128 + (((ks * 32 + lhi * 8) * 2) ^ ((prow & 7) << 4)));
      }
#pragma unroll
      for (int dm = 0; dm < 16; ++dm) {
        int vrow = dm * 16 + l15;
        s16x8 vf = *(const s16x8*)(ldsV + vrow * 128 + (((ks * 32 + lhi * 8) * 2) ^ ((vrow & 7) << 4)));
        ctx[0][dm] = mfma16(pf[0], vf, ctx[0][dm]);
        ctx[1][dm] = mfma16(pf[1], vf, ctx[1][dm]);
      }
    }
    __builtin_amdgcn_s_setprio(0);
    __syncthreads();   // all waves done with ldsK/ldsV/ldsP before next stage
  }

  // reduce l across the 16-lane group
#pragma unroll
  for (int mk = 1; mk <= 8; mk <<= 1)
#pragma unroll
    for (int f = 0; f < 2; ++f)
#pragma unroll
      for (int r = 0; r < 4; ++r)
        l_run[f][r] += __shfl_xor(l_run[f][r], mk, 64);

  if (DIRECT) {
#pragma unroll
    for (int f = 0; f < 2; ++f)
#pragma unroll
      for (int r = 0; r < 4; ++r) {
        float inv = 1.0f / l_run[f][r];
        size_t rowb = (size_t)(q0 + f * 16 + lhi * 4 + r) * 256 + l15;
#pragma unroll
        for (int dm = 0; dm < 16; ++dm)
          CX[rowb + dm * 16] = (unsigned short)f2bf(ctx[f][dm][r] * inv);
      }
  } else {
#pragma unroll
    for (int f = 0; f < 2; ++f)
#pragma unroll
      for (int r = 0; r < 4; ++r) {
        size_t rowb = (size_t)sp * 8192 * 256 +
                      (size_t)(q0 + f * 16 + lhi * 4 + r) * 256 + l15;
        if (PACC_BF16) {
#pragma unroll
          for (int dm = 0; dm < 16; ++dm)
            ((unsigned short*)pacc)[rowb + dm * 16] = (unsigned short)f2bf(ctx[f][dm][r]);
        } else {
#pragma unroll
          for (int dm = 0; dm < 16; ++dm)
            ((float*)pacc)[rowb + dm * 16] = ctx[f][dm][r];
        }
      }
    if (l15 == 0) {
#pragma unroll
      for (int f = 0; f < 2; ++f)
#pragma unroll
        for (int r = 0; r < 4; ++r) {
          pm[(size_t)sp * 8192 + q0 + f * 16 + lhi * 4 + r] = m_run[f][r];
          pl[(size_t)sp * 8192 + q0 + f * 16 + lhi * 4 + r] = l_run[f][r];
        }
    }
  }
}

// ---------------------------------------------------------------------------
// Combine SPLIT=8 partials -> context bf16
// ---------------------------------------------------------------------------
template<bool PACC_BF16>
__global__ __launch_bounds__(256)
void combine_kernel(const void* __restrict__ pacc, const float* __restrict__ pm,
                    const float* __restrict__ pl, unsigned short* __restrict__ cx)
{
  const int row = blockIdx.x;
  const int d = threadIdx.x;
  float M = MINIT;
#pragma unroll
  for (int s = 0; s < 8; ++s) M = fmaxf(M, pm[s * 8192 + row]);
  float L = 0.f, v = 0.f;
#pragma unroll
  for (int s = 0; s < 8; ++s) {
    float ws = __builtin_amdgcn_exp2f((pm[s * 8192 + row] - M) * LOG2E);
    L += ws * pl[s * 8192 + row];
    size_t idx = (size_t)s * 8192 * 256 + (size_t)row * 256 + d;
    float pv;
    if (PACC_BF16) {
      union { unsigned u; float f; } c; c.u = (unsigned)((const unsigned short*)pacc)[idx] << 16;
      pv = c.f;
    } else {
      pv = ((const float*)pacc)[idx];
    }
    v += ws * pv;
  }
  cx[(size_t)row * 256 + d] = (unsigned short)f2bf(v / L);
}

// ---------------------------------------------------------------------------
extern "C" void kernel_launch(void* const* d_in, const int* in_sizes, int n_in,
                              void* d_out, int out_size, void* d_ws, size_t ws_size,
                              hipStream_t stream)
{
  const float* E  = (const float*)d_in[0];
  const int*  adj = (const int*)d_in[1];
  const float* Wq = (const float*)d_in[2];
  const float* bq = (const float*)d_in[3];
  const float* Wk = (const float*)d_in[4];
  const float* bk = (const float*)d_in[5];
  const float* Wv = (const float*)d_in[6];
  const float* bv = (const float*)d_in[7];
  const float* Wo = (const float*)d_in[8];
  const float* bo = (const float*)d_in[9];

  char* ws = (char*)d_ws;
  unsigned short* Qb = (unsigned short*)(ws);
  unsigned short* Kb = (unsigned short*)(ws + ((size_t)4 << 20));
  unsigned short* VT = (unsigned short*)(ws + ((size_t)8 << 20));
  unsigned short* CX = (unsigned short*)(ws + ((size_t)12 << 20));
  unsigned long long* bm = (unsigned long long*)(ws + ((size_t)16 << 20));
  char* pacc = ws + ((size_t)24 << 20);

  dim3 b(256);
  // adjacency -> bitmask (8MB); independent of projections
  hipLaunchKernelGGL(repack_kernel, dim3(8192), b, 0, stream, adj, bm);
  // fused Q/K/V projections (Q pre-scaled by 1/sqrt(256)); V written transposed
  hipLaunchKernelGGL(qkv_kernel, dim3(128, 4), b, 0, stream,
                     E, Wq, bq, Wk, bk, Wv, bv, Qb, Kb, VT);

  const size_t PACC_F32_BYTES  = (size_t)8 * 8192 * 256 * 4;   // 64MB
  const size_t PACC_BF16_BYTES = (size_t)8 * 8192 * 256 * 2;   // 32MB
  const size_t PMPL = (size_t)8 * 8192 * 4;                    // 256KB each
  const size_t NEED_F32  = ((size_t)24 << 20) + PACC_F32_BYTES + 2 * PMPL;  // 88.5MB
  const size_t NEED_BF16 = ((size_t)24 << 20) + PACC_BF16_BYTES + 2 * PMPL; // 56.5MB

  if (ws_size >= NEED_F32) {
    float* pm = (float*)(pacc + PACC_F32_BYTES);
    float* pl = pm + 8 * 8192;
    hipLaunchKernelGGL((attn_kernel<8, false, false>), dim3(512), b, 0, stream,
                       Qb, (const char*)Kb, (const char*)VT, bm, pacc, pm, pl, CX);
    hipLaunchKernelGGL((combine_kernel<false>), dim3(8192), b, 0, stream, pacc, pm, pl, CX);
  } else if (ws_size >= NEED_BF16) {
    float* pm = (float*)(pacc + PACC_BF16_BYTES);
    float* pl = pm + 8 * 8192;
    hipLaunchKernelGGL((attn_kernel<8, false, true>), dim3(512), b, 0, stream,
                       Qb, (const char*)Kb, (const char*)VT, bm, pacc, pm, pl, CX);
    hipLaunchKernelGGL((combine_kernel<true>), dim3(8192), b, 0, stream, pacc, pm, pl, CX);
  } else {
    // fallback: no split, direct-normalized write (64 blocks, slow but correct)
    float* pm = (float*)pacc; float* pl = pm + 8192;
    hipLaunchKernelGGL((attn_kernel<1, true, false>), dim3(64), b, 0, stream,
                       Qb, (const char*)Kb, (const char*)VT, bm, pacc, pm, pl, CX);
  }
  // output projection (bf16 A, f32 out)
  hipLaunchKernelGGL(projo_kernel, dim3(128, 4), b, 0, stream, CX, Wo, bo, (float*)d_out);
}

// Round 5
// 618.539 us; speedup vs baseline: 1.1592x; 1.1592x over previous
//
#include <hip/hip_runtime.h>
#include <hip/hip_bf16.h>

// SwarmAttentionHead: out = softmax(mask(QK^T/sqrt(D))) @ V @ Wo^T + bo
// N=8192, D=256. bf16 MFMA everywhere, f32 softmax/accum.
// Adjacency consumed directly in attn via coalesced loads + __ballot (no repack).
//
// ws layout:
//   [0,   4M)  Qb  bf16 [8192][256]   (pre-scaled by 1/16)
//   [4M,  8M)  Kb  bf16 [8192][256]
//   [8M, 12M)  VT  bf16 [256][8192]   (V transposed)
//   [12M,16M)  CX  bf16 [8192][256]   (context)
//   [16M, ..)  pacc [8][8192][256] f32 (80.5M) or bf16 (48.5M); pm/pl after

#define LOG2E 1.44269504088896340736f
#define MASKVAL -3.0e38f   // masked score sentinel
#define MINIT   -1.0e38f   // running-max init; MUST differ from MASKVAL (x-x=0 bug)

using f32x4 = __attribute__((ext_vector_type(4))) float;
using s16x8 = __attribute__((ext_vector_type(8))) short;
using s16x4 = __attribute__((ext_vector_type(4))) short;

__device__ __forceinline__ void gl_lds16(void* l, const void* g) {
  __builtin_amdgcn_global_load_lds(
      (const __attribute__((address_space(1))) void*)g,
      (__attribute__((address_space(3))) void*)l, 16, 0, 0);
}

__device__ __forceinline__ short f2bf(float x) {
  union { float f; unsigned u; } v; v.f = x;
  unsigned r = v.u + 0x7fffu + ((v.u >> 16) & 1u);   // RNE, finite inputs only
  return (short)(r >> 16);
}

__device__ __forceinline__ s16x8 cvt_frag(f32x4 a, f32x4 b) {
  s16x8 r;
  r[0]=f2bf(a[0]); r[1]=f2bf(a[1]); r[2]=f2bf(a[2]); r[3]=f2bf(a[3]);
  r[4]=f2bf(b[0]); r[5]=f2bf(b[1]); r[6]=f2bf(b[2]); r[7]=f2bf(b[3]);
  return r;
}

__device__ __forceinline__ f32x4 mfma16(s16x8 a, s16x8 b, f32x4 c) {
  return __builtin_amdgcn_mfma_f32_16x16x32_bf16(a, b, c, 0, 0, 0);
}

// ---------------------------------------------------------------------------
// Fused QKV projection — LDS-free, barrier-free register GEMM.
// Block 256 = 4 waves (2x2); wave does 32 rows x 32 cols; grid (128,4).
// A/B frags loaded directly from global (W is L2-hot; E overlap via TLP).
// ---------------------------------------------------------------------------
__global__ __launch_bounds__(256, 2)
void qkv_kernel(const float* __restrict__ E,
                const float* __restrict__ Wq, const float* __restrict__ bq,
                const float* __restrict__ Wk, const float* __restrict__ bk,
                const float* __restrict__ Wv, const float* __restrict__ bv,
                unsigned short* __restrict__ Qb, unsigned short* __restrict__ Kb,
                unsigned short* __restrict__ VT)
{
  const int tid = threadIdx.x, lane = tid & 63, w = tid >> 6;
  const int wr = w >> 1, wc = w & 1;
  const int l15 = lane & 15, lhi = lane >> 4;
  const int m0 = blockIdx.x * 64 + wr * 32;
  const int n0 = blockIdx.y * 64 + wc * 32;

  // A fragments: E rows m0+m*16+l15, k = ks*32 + lhi*8 .. +7
  s16x8 af[2][8];
#pragma unroll
  for (int m = 0; m < 2; ++m) {
    const float* ap = E + (size_t)(m0 + m * 16 + l15) * 256 + lhi * 8;
#pragma unroll
    for (int ks = 0; ks < 8; ++ks) {
      f32x4 lo = *(const f32x4*)(ap + ks * 32);
      f32x4 hi = *(const f32x4*)(ap + ks * 32 + 4);
      af[m][ks] = cvt_frag(lo, hi);
    }
  }

  const float* Ws[3] = {Wq, Wk, Wv};
  f32x4 acc[3][2][2] = {};
#pragma unroll
  for (int mtx = 0; mtx < 3; ++mtx)
#pragma unroll
    for (int n = 0; n < 2; ++n) {
      const float* bp = Ws[mtx] + (size_t)(n0 + n * 16 + l15) * 256 + lhi * 8;
#pragma unroll
      for (int ks = 0; ks < 8; ++ks) {
        f32x4 lo = *(const f32x4*)(bp + ks * 32);
        f32x4 hi = *(const f32x4*)(bp + ks * 32 + 4);
        s16x8 bf = cvt_frag(lo, hi);
#pragma unroll
        for (int m = 0; m < 2; ++m)
          acc[mtx][m][n] = mfma16(af[m][ks], bf, acc[mtx][m][n]);
      }
    }

  // C row = m0+m*16+lhi*4+r, col = n0+n*16+l15
#pragma unroll
  for (int n = 0; n < 2; ++n) {
    int col = n0 + n * 16 + l15;
    float bvq = bq[col], bvk = bk[col], bvv = bv[col];
#pragma unroll
    for (int m = 0; m < 2; ++m) {
      int rbase = m0 + m * 16 + lhi * 4;
#pragma unroll
      for (int r = 0; r < 4; ++r) {
        Qb[(size_t)(rbase + r) * 256 + col] = (unsigned short)f2bf((acc[0][m][n][r] + bvq) * 0.0625f);
        Kb[(size_t)(rbase + r) * 256 + col] = (unsigned short)f2bf(acc[1][m][n][r] + bvk);
      }
      s16x4 pk;
#pragma unroll
      for (int r = 0; r < 4; ++r) pk[r] = f2bf(acc[2][m][n][r] + bvv);
      *(s16x4*)(VT + (size_t)col * 8192 + rbase) = pk;
    }
  }
}

// ---------------------------------------------------------------------------
// Output projection — same LDS-free structure, bf16 A, f32 out.
// ---------------------------------------------------------------------------
__global__ __launch_bounds__(256, 2)
void projo_kernel(const unsigned short* __restrict__ CX, const float* __restrict__ Wo,
                  const float* __restrict__ bo, float* __restrict__ outp)
{
  const int tid = threadIdx.x, lane = tid & 63, w = tid >> 6;
  const int wr = w >> 1, wc = w & 1;
  const int l15 = lane & 15, lhi = lane >> 4;
  const int m0 = blockIdx.x * 64 + wr * 32;
  const int n0 = blockIdx.y * 64 + wc * 32;

  s16x8 af[2][8];
#pragma unroll
  for (int m = 0; m < 2; ++m) {
    const unsigned short* ap = CX + (size_t)(m0 + m * 16 + l15) * 256 + lhi * 8;
#pragma unroll
    for (int ks = 0; ks < 8; ++ks) af[m][ks] = *(const s16x8*)(ap + ks * 32);
  }

  f32x4 acc[2][2] = {};
#pragma unroll
  for (int n = 0; n < 2; ++n) {
    const float* bp = Wo + (size_t)(n0 + n * 16 + l15) * 256 + lhi * 8;
#pragma unroll
    for (int ks = 0; ks < 8; ++ks) {
      f32x4 lo = *(const f32x4*)(bp + ks * 32);
      f32x4 hi = *(const f32x4*)(bp + ks * 32 + 4);
      s16x8 bf = cvt_frag(lo, hi);
#pragma unroll
      for (int m = 0; m < 2; ++m)
        acc[m][n] = mfma16(af[m][ks], bf, acc[m][n]);
    }
  }

#pragma unroll
  for (int n = 0; n < 2; ++n) {
    int col = n0 + n * 16 + l15;
    float bv = bo[col];
#pragma unroll
    for (int m = 0; m < 2; ++m) {
      int rbase = m0 + m * 16 + lhi * 4;
#pragma unroll
      for (int r = 0; r < 4; ++r)
        outp[(size_t)(rbase + r) * 256 + col] = acc[m][n][r] + bv;
    }
  }
}

// ---------------------------------------------------------------------------
// Flash attention. Block = 512 thr (8 waves), BM=256 (32 q-rows/wave),
// KVBLK=32, K/V double-buffered (80KB LDS, 1 block/CU), ONE barrier/tile:
// stage(t+1) issued at tile top, drained by the end-of-tile barrier.
// Adjacency read directly (coalesced, lane=col) + __ballot row-masks.
// ---------------------------------------------------------------------------
template<int SPLIT, bool DIRECT, bool PACC_BF16>
__global__ __launch_bounds__(512, 2)
void attn_kernel(const unsigned short* __restrict__ Qb, const char* __restrict__ Kb,
                 const char* __restrict__ VbT, const int* __restrict__ adj,
                 void* __restrict__ pacc, float* __restrict__ pm,
                 float* __restrict__ pl, unsigned short* __restrict__ CX)
{
  __shared__ __align__(16) char ldsK[2][16384];  // [32 kv][512B], swz ((row&7)<<4)
  __shared__ __align__(16) char ldsV[2][16384];  // [256 d][64B],  swz ((row&3)<<4)
  __shared__ __align__(16) char ldsP[8][2048];   // per wave [32 q][64B], swz ((row&3)<<4)
  const int tid = threadIdx.x, lane = tid & 63, w = tid >> 6;
  const int l15 = lane & 15, lhi = lane >> 4;
  const int qt = blockIdx.x / SPLIT, sp = blockIdx.x % SPLIT;
  const int q0 = qt * 256 + w * 32;          // wave's 32 q-rows
  char* myP = ldsP[w];
  const int kv_begin = sp * (8192 / SPLIT);
  const int NT = 8192 / SPLIT / 32;

  // Q fragments: 2 frags x 8 k-slices (pre-scaled by 1/16 in Qb)
  s16x8 qf[2][8];
#pragma unroll
  for (int f = 0; f < 2; ++f) {
    const unsigned short* qp = Qb + (size_t)(q0 + f * 16 + l15) * 256 + lhi * 8;
#pragma unroll
    for (int ks = 0; ks < 8; ++ks) qf[f][ks] = *(const s16x8*)(qp + ks * 32);
  }

  f32x4 ctx[2][16] = {};
  float m_run[2][4], l_run[2][4];
#pragma unroll
  for (int f = 0; f < 2; ++f)
#pragma unroll
    for (int r = 0; r < 4; ++r) { m_run[f][r] = MINIT; l_run[f][r] = 0.f; }

  auto STAGE = [&](int buf, int tt) {
    const int kv0 = kv_begin + tt * 32;
    const char* kg = Kb + (size_t)kv0 * 512;
#pragma unroll
    for (int i = 0; i < 2; ++i) {                 // K: 16KB
      int o = tid * 16 + i * 8192;
      int row = o >> 9, inrow = o & 511;
      gl_lds16(&ldsK[buf][o], kg + row * 512 + (inrow ^ ((row & 7) << 4)));
    }
#pragma unroll
    for (int i = 0; i < 2; ++i) {                 // V^T: 16KB
      int o = tid * 16 + i * 8192;
      int row = o >> 6, inrow = o & 63;
      gl_lds16(&ldsV[buf][o], VbT + (size_t)row * 16384 + (size_t)kv0 * 2 + (inrow ^ ((row & 3) << 4)));
    }
  };

  STAGE(0, 0);
  __syncthreads();                                // buf0 ready

  // adjacency base: lane covers (row-parity, col): row = 2j + (lane>>5), col = lane&31
  const int* abase = adj + (size_t)(q0 + (lane >> 5)) * 8192 + (lane & 31);

  for (int t = 0; t < NT; ++t) {
    const int cur = t & 1;
    const int kv0 = kv_begin + t * 32;

    // adjacency loads for THIS tile (consumed after QK^T — latency hidden)
    int av[16];
    {
      const int* ap = abase + kv0;
#pragma unroll
      for (int j = 0; j < 16; ++j) av[j] = ap[(size_t)j * 2 * 8192];
    }
    if (t + 1 < NT) STAGE(cur ^ 1, t + 1);        // prefetch, drained at end barrier

    // S = Q @ K^T
    f32x4 sacc[2][2] = {};
    __builtin_amdgcn_s_setprio(1);
#pragma unroll
    for (int ks = 0; ks < 8; ++ks)
#pragma unroll
      for (int cg = 0; cg < 2; ++cg) {
        int row = cg * 16 + l15;
        s16x8 kf = *(const s16x8*)(&ldsK[cur][row * 512 + ((ks * 64 + lhi * 16) ^ ((row & 7) << 4))]);
        sacc[0][cg] = mfma16(qf[0][ks], kf, sacc[0][cg]);
        sacc[1][cg] = mfma16(qf[1][ks], kf, sacc[1][cg]);
      }
    __builtin_amdgcn_s_setprio(0);

    // build per-row 32-bit masks via ballot; lane keeps rows (f*16 + lhi*4 + r)
    unsigned bmv[2][4] = {};
#pragma unroll
    for (int j = 0; j < 16; ++j) {
      unsigned long long b = __ballot(av[j] != 0);
      unsigned lo = (unsigned)b, hi = (unsigned)(b >> 32);
      const int row0 = 2 * j;                     // row0 even, row1 = row0+1
      const int f = row0 >> 4, g = (row0 >> 2) & 3, r = row0 & 3;
      bmv[f][r]     = (lhi == g) ? lo : bmv[f][r];
      bmv[f][r + 1] = (lhi == g) ? hi : bmv[f][r + 1];
    }

    // fold mask pre-max (reference semantics)
#pragma unroll
    for (int f = 0; f < 2; ++f)
#pragma unroll
      for (int r = 0; r < 4; ++r) {
        unsigned ms = bmv[f][r] >> l15;
#pragma unroll
        for (int cg = 0; cg < 2; ++cg)
          if (!((ms >> (cg * 16)) & 1u)) sacc[f][cg][r] = MASKVAL;
      }

    // row max across cg then the 16 lanes
    float tmax[2][4];
#pragma unroll
    for (int f = 0; f < 2; ++f)
#pragma unroll
      for (int r = 0; r < 4; ++r)
        tmax[f][r] = fmaxf(sacc[f][0][r], sacc[f][1][r]);
#pragma unroll
    for (int mk = 1; mk <= 8; mk <<= 1)
#pragma unroll
      for (int f = 0; f < 2; ++f)
#pragma unroll
        for (int r = 0; r < 4; ++r)
          tmax[f][r] = fmaxf(tmax[f][r], __shfl_xor(tmax[f][r], mk, 64));

    // T13 defer-max
    float need = MASKVAL;
#pragma unroll
    for (int f = 0; f < 2; ++f)
#pragma unroll
      for (int r = 0; r < 4; ++r)
        need = fmaxf(need, tmax[f][r] - m_run[f][r]);
    if (!__all(need <= 8.0f)) {
#pragma unroll
      for (int f = 0; f < 2; ++f) {
        f32x4 fv;
#pragma unroll
        for (int r = 0; r < 4; ++r) {
          float mnew = fmaxf(m_run[f][r], tmax[f][r]);
          float fs = __builtin_amdgcn_exp2f((m_run[f][r] - mnew) * LOG2E);
          m_run[f][r] = mnew; l_run[f][r] *= fs; fv[r] = fs;
        }
#pragma unroll
        for (int dm = 0; dm < 16; ++dm) ctx[f][dm] *= fv;
      }
    }

    // p = e^{s-m}, accumulate l, stage P (wave-private LDS; no barrier needed)
#pragma unroll
    for (int f = 0; f < 2; ++f)
#pragma unroll
      for (int cg = 0; cg < 2; ++cg)
#pragma unroll
        for (int r = 0; r < 4; ++r) {
          float p = __builtin_amdgcn_exp2f((sacc[f][cg][r] - m_run[f][r]) * LOG2E);
          l_run[f][r] += p;
          int row = f * 16 + lhi * 4 + r;
          int cb = (cg * 16 + l15) * 2;
          *(short*)(myP + row * 64 + (cb ^ ((row & 3) << 4))) = f2bf(p);
        }

    // ctx += P @ V
    __builtin_amdgcn_s_setprio(1);
    s16x8 pf[2];
#pragma unroll
    for (int f = 0; f < 2; ++f) {
      int prow = f * 16 + l15;
      pf[f] = *(const s16x8*)(myP + prow * 64 + ((lhi * 16) ^ ((prow & 3) << 4)));
    }
#pragma unroll
    for (int dm = 0; dm < 16; ++dm) {
      int vrow = dm * 16 + l15;
      s16x8 vf = *(const s16x8*)(&ldsV[cur][vrow * 64 + ((lhi * 16) ^ ((vrow & 3) << 4))]);
      ctx[0][dm] = mfma16(pf[0], vf, ctx[0][dm]);
      ctx[1][dm] = mfma16(pf[1], vf, ctx[1][dm]);
    }
    __builtin_amdgcn_s_setprio(0);

    __syncthreads();   // drains stage(t+1); all waves done with buf[cur]
  }

  // reduce l across the 16-lane group
#pragma unroll
  for (int mk = 1; mk <= 8; mk <<= 1)
#pragma unroll
    for (int f = 0; f < 2; ++f)
#pragma unroll
      for (int r = 0; r < 4; ++r)
        l_run[f][r] += __shfl_xor(l_run[f][r], mk, 64);

  if (DIRECT) {
#pragma unroll
    for (int f = 0; f < 2; ++f)
#pragma unroll
      for (int r = 0; r < 4; ++r) {
        float inv = 1.0f / l_run[f][r];
        size_t rowb = (size_t)(q0 + f * 16 + lhi * 4 + r) * 256 + l15;
#pragma unroll
        for (int dm = 0; dm < 16; ++dm)
          CX[rowb + dm * 16] = (unsigned short)f2bf(ctx[f][dm][r] * inv);
      }
  } else {
#pragma unroll
    for (int f = 0; f < 2; ++f)
#pragma unroll
      for (int r = 0; r < 4; ++r) {
        size_t rowb = (size_t)sp * 8192 * 256 +
                      (size_t)(q0 + f * 16 + lhi * 4 + r) * 256 + l15;
        if (PACC_BF16) {
#pragma unroll
          for (int dm = 0; dm < 16; ++dm)
            ((unsigned short*)pacc)[rowb + dm * 16] = (unsigned short)f2bf(ctx[f][dm][r]);
        } else {
#pragma unroll
          for (int dm = 0; dm < 16; ++dm)
            ((float*)pacc)[rowb + dm * 16] = ctx[f][dm][r];
        }
      }
    if (l15 == 0) {
#pragma unroll
      for (int f = 0; f < 2; ++f)
#pragma unroll
        for (int r = 0; r < 4; ++r) {
          pm[(size_t)sp * 8192 + q0 + f * 16 + lhi * 4 + r] = m_run[f][r];
          pl[(size_t)sp * 8192 + q0 + f * 16 + lhi * 4 + r] = l_run[f][r];
        }
    }
  }
}

// ---------------------------------------------------------------------------
// Combine SPLIT=8 partials -> context bf16
// ---------------------------------------------------------------------------
template<bool PACC_BF16>
__global__ __launch_bounds__(256)
void combine_kernel(const void* __restrict__ pacc, const float* __restrict__ pm,
                    const float* __restrict__ pl, unsigned short* __restrict__ cx)
{
  const int row = blockIdx.x;
  const int d = threadIdx.x;
  float M = MINIT;
#pragma unroll
  for (int s = 0; s < 8; ++s) M = fmaxf(M, pm[s * 8192 + row]);
  float L = 0.f, v = 0.f;
#pragma unroll
  for (int s = 0; s < 8; ++s) {
    float ws = __builtin_amdgcn_exp2f((pm[s * 8192 + row] - M) * LOG2E);
    L += ws * pl[s * 8192 + row];
    size_t idx = (size_t)s * 8192 * 256 + (size_t)row * 256 + d;
    float pv;
    if (PACC_BF16) {
      union { unsigned u; float f; } c; c.u = (unsigned)((const unsigned short*)pacc)[idx] << 16;
      pv = c.f;
    } else {
      pv = ((const float*)pacc)[idx];
    }
    v += ws * pv;
  }
  cx[(size_t)row * 256 + d] = (unsigned short)f2bf(v / L);
}

// ---------------------------------------------------------------------------
extern "C" void kernel_launch(void* const* d_in, const int* in_sizes, int n_in,
                              void* d_out, int out_size, void* d_ws, size_t ws_size,
                              hipStream_t stream)
{
  const float* E  = (const float*)d_in[0];
  const int*  adj = (const int*)d_in[1];
  const float* Wq = (const float*)d_in[2];
  const float* bq = (const float*)d_in[3];
  const float* Wk = (const float*)d_in[4];
  const float* bk = (const float*)d_in[5];
  const float* Wv = (const float*)d_in[6];
  const float* bv = (const float*)d_in[7];
  const float* Wo = (const float*)d_in[8];
  const float* bo = (const float*)d_in[9];

  char* ws = (char*)d_ws;
  unsigned short* Qb = (unsigned short*)(ws);
  unsigned short* Kb = (unsigned short*)(ws + ((size_t)4 << 20));
  unsigned short* VT = (unsigned short*)(ws + ((size_t)8 << 20));
  unsigned short* CX = (unsigned short*)(ws + ((size_t)12 << 20));
  char* pacc = ws + ((size_t)16 << 20);

  // fused QKV projection (LDS-free register GEMM)
  hipLaunchKernelGGL(qkv_kernel, dim3(128, 4), dim3(256), 0, stream,
                     E, Wq, bq, Wk, bk, Wv, bv, Qb, Kb, VT);

  const size_t PACC_F32_BYTES  = (size_t)8 * 8192 * 256 * 4;   // 64MB
  const size_t PACC_BF16_BYTES = (size_t)8 * 8192 * 256 * 2;   // 32MB
  const size_t PMPL = (size_t)8 * 8192 * 4;                    // 256KB each
  const size_t NEED_F32  = ((size_t)16 << 20) + PACC_F32_BYTES + 2 * PMPL;  // 80.5MB
  const size_t NEED_BF16 = ((size_t)16 << 20) + PACC_BF16_BYTES + 2 * PMPL; // 48.5MB

  if (ws_size >= NEED_F32) {
    float* pm = (float*)(pacc + PACC_F32_BYTES);
    float* pl = pm + 8 * 8192;
    hipLaunchKernelGGL((attn_kernel<8, false, false>), dim3(256), dim3(512), 0, stream,
                       Qb, (const char*)Kb, (const char*)VT, adj, pacc, pm, pl, CX);
    hipLaunchKernelGGL((combine_kernel<false>), dim3(8192), dim3(256), 0, stream, pacc, pm, pl, CX);
  } else if (ws_size >= NEED_BF16) {
    float* pm = (float*)(pacc + PACC_BF16_BYTES);
    float* pl = pm + 8 * 8192;
    hipLaunchKernelGGL((attn_kernel<8, false, true>), dim3(256), dim3(512), 0, stream,
                       Qb, (const char*)Kb, (const char*)VT, adj, pacc, pm, pl, CX);
    hipLaunchKernelGGL((combine_kernel<true>), dim3(8192), dim3(256), 0, stream, pacc, pm, pl, CX);
  } else {
    // fallback: no split, direct-normalized write (32 blocks, slow but correct)
    float* pm = (float*)pacc; float* pl = pm + 8192;
    hipLaunchKernelGGL((attn_kernel<1, true, false>), dim3(32), dim3(512), 0, stream,
                       Qb, (const char*)Kb, (const char*)VT, adj, pacc, pm, pl, CX);
  }
  // output projection (bf16 A, f32 out)
  hipLaunchKernelGGL(projo_kernel, dim3(128, 4), dim3(256), 0, stream, CX, Wo, bo, (float*)d_out);
}